// Round 12
// baseline (309.684 us; speedup 1.0000x reference)
//
#include <hip/hip_runtime.h>
#include <stdint.h>

typedef __bf16 bf16x8 __attribute__((ext_vector_type(8)));
typedef float f32x4 __attribute__((ext_vector_type(4)));
typedef unsigned short ushort8 __attribute__((ext_vector_type(8)));
typedef unsigned short u16x4 __attribute__((ext_vector_type(4)));

#define S_DIM 1024
#define R_DIM 256
#define DMODEL 256
#define EPSV 9.5367431640625e-07f
#define ASTRIDE 264  // 256 + 8 bf16 pad
#define OSTRIDE 72   // 64 + 8 pad

__device__ __forceinline__ unsigned short f2bf(float f) {
  uint32_t u = __float_as_uint(f);
  u += 0x7fffu + ((u >> 16) & 1u);
  return (unsigned short)(u >> 16);
}
__device__ __forceinline__ float bf2f(unsigned short s) {
  return __uint_as_float(((uint32_t)s) << 16);
}
__device__ __forceinline__ bf16x8 ldfrag(const unsigned short* p) {
  return __builtin_bit_cast(bf16x8, *(const ushort8*)p);
}
__device__ __forceinline__ bf16x8 pack8(float4 a, float4 b) {
  ushort8 u;
  u[0] = f2bf(a.x); u[1] = f2bf(a.y); u[2] = f2bf(a.z); u[3] = f2bf(a.w);
  u[4] = f2bf(b.x); u[5] = f2bf(b.y); u[6] = f2bf(b.z); u[7] = f2bf(b.w);
  return __builtin_bit_cast(bf16x8, u);
}

// ---------- all weight packing in one launch ----------
// B-frag layout: elem j of lane l for (kstep,ct) = W[kstep*32+(l>>4)*8+j][ct*16+(l&15)]
__global__ __launch_bounds__(256) void pack_all_kernel(const float* __restrict__ Wk,
                                                       const float* __restrict__ Wv,
                                                       const float* __restrict__ Wg,
                                                       const float* __restrict__ Wo,
                                                       unsigned short* __restrict__ wkv,
                                                       unsigned short* __restrict__ wg_p,
                                                       unsigned short* __restrict__ wo_p) {
  int bid = blockIdx.x;
  int tid = threadIdx.x;
  if (bid < 64) {
    int idx = bid * 256 + tid;
    int j = idx & 7, lane = (idx >> 3) & 63, t = idx >> 9;
    int ct = t & 3, kstep = t >> 2;
    int k = kstep * 32 + ((lane >> 4) << 3) + j;
    int col = ct * 16 + (lane & 15);
    float w = (col < 32) ? Wk[k * 32 + col] : Wv[k * 32 + (col - 32)];
    wkv[idx] = f2bf(w);
  } else {
    const float* W = (bid < 320) ? Wg : Wo;
    unsigned short* out = (bid < 320) ? wg_p : wo_p;
    int idx = ((bid < 320) ? (bid - 64) : (bid - 320)) * 256 + tid;
    int j = idx & 7, lane = (idx >> 3) & 63, t = idx >> 9;
    int ct = t & 15, kstep = t >> 4;
    int k = kstep * 32 + ((lane >> 4) << 3) + j;
    int col = ct * 16 + (lane & 15);
    out[idx] = f2bf(W[k * 256 + col]);
  }
}

// ---------- pool: 512 thr (8 waves), XCD-swizzled ----------
template <int USE_ECHO>
__global__ __launch_bounds__(512, 4) void pool_kernel(const float* __restrict__ q_data,
                                                      const float* __restrict__ q_mask,
                                                      float* __restrict__ psum,
                                                      float* __restrict__ pmask,
                                                      unsigned short* __restrict__ qb16) {
  __shared__ float mlds[256];
  __shared__ float wred[4];
  __shared__ f32x4 red[8 * 64];
  int bid0 = blockIdx.x;
  int bid = (bid0 & 7) * 128 + (bid0 >> 3);  // XCD-bijective (nwg=1024)
  int tid = threadIdx.x;
  int r = bid >> 2, c = bid & 3;
  int s0 = c * 256;
  if (tid < 256) {
    float m = q_mask[r * S_DIM + s0 + tid];
    mlds[tid] = m;
    float ms = m;
    for (int off = 32; off; off >>= 1) ms += __shfl_down(ms, off);
    if ((tid & 63) == 0) wred[tid >> 6] = ms;
  }
  __syncthreads();
  if (tid == 0) pmask[r * 4 + c] = wred[0] + wred[1] + wred[2] + wred[3];
  int wv = tid >> 6, ln = tid & 63;  // wave wv handles rows wv, wv+8, ... (32 rows)
  size_t rowbase = (size_t)(r * S_DIM + s0);
  const float* bp = q_data + (rowbase + wv) * DMODEL + ln * 4;
  unsigned short* ebp = USE_ECHO ? (qb16 + (rowbase + wv) * DMODEL + ln * 4) : nullptr;
  f32x4 acc4 = {};
  #pragma unroll 8
  for (int it = 0; it < 32; it++) {
    float4 v = *(const float4*)(bp + (size_t)it * 8 * DMODEL);
    float mm = mlds[it * 8 + wv];
    acc4[0] += v.x * mm; acc4[1] += v.y * mm;
    acc4[2] += v.z * mm; acc4[3] += v.w * mm;
    if (USE_ECHO) {
      u16x4 e;
      e[0] = f2bf(v.x); e[1] = f2bf(v.y); e[2] = f2bf(v.z); e[3] = f2bf(v.w);
      *(u16x4*)(ebp + (size_t)it * 8 * DMODEL) = e;
    }
  }
  red[wv * 64 + ln] = acc4;
  __syncthreads();
  if (tid < 256) {
    int c4 = tid >> 2, cm = tid & 3;
    float sum = 0.f;
    #pragma unroll
    for (int k = 0; k < 8; k++) sum += red[k * 64 + c4][cm];
    psum[(r * 4 + c) * 256 + tid] = sum;
  }
}

// ---------- kv projection: BM=16, global_load_lds fp32 staging (swizzled src + swizzled read) ----------
__global__ __launch_bounds__(256, 8) void kv_kernel(const float* __restrict__ m_data,
                                                    const unsigned short* __restrict__ wkv,
                                                    unsigned short* __restrict__ kb,
                                                    unsigned short* __restrict__ vb_t) {
  __shared__ __align__(16) float Af[16 * 256];  // 16 KB linear (DMA dest); reused as O [16][OSTRIDE]
  int bid0 = blockIdx.x;
  int bid = (bid0 & 7) * 2048 + (bid0 >> 3);    // XCD-bijective (nwg=16384)
  int tid = threadIdx.x;
  int wave = tid >> 6, lane = tid & 63;
  int g = lane >> 4, lr = lane & 15;
  int row0 = bid * 16;
  // stage: 16 rows x 1 KB via global_load_lds(16B); source pre-swizzled (XOR (C&7)<<5)
  #pragma unroll
  for (int i = 0; i < 4; i++) {
    int C = wave * 4 + i;
    const char* gsrc = (const char*)(m_data + (size_t)(row0 + C) * DMODEL)
                     + ((lane * 16) ^ ((C & 7) << 5));
    __builtin_amdgcn_global_load_lds(
        (const __attribute__((address_space(1))) void*)gsrc,
        (__attribute__((address_space(3))) void*)(&Af[C * 256]), 16, 0, 0);
  }
  __syncthreads();
  // MFMA: all waves cover rows 0..15; wave index = ct; pack fp32->bf16 on LDS read
  f32x4 acc = {};
  #pragma unroll
  for (int ks = 0; ks < 8; ks++) {
    int boff = (ks * 128 + g * 32) ^ ((lr & 7) << 5);
    const float4* fp = (const float4*)((const char*)Af + lr * 1024 + boff);
    bf16x8 af = pack8(fp[0], fp[1]);
    bf16x8 bf = ldfrag(&wkv[((ks * 4 + wave) << 9) + lane * 8]);
    acc = __builtin_amdgcn_mfma_f32_16x16x32_bf16(af, bf, acc, 0, 0, 0);
  }
  __syncthreads();  // all reads done; reuse Af as O
  unsigned short* O = (unsigned short*)Af;
  #pragma unroll
  for (int rg = 0; rg < 4; rg++)
    O[(g * 4 + rg) * OSTRIDE + wave * 16 + lr] = f2bf(acc[rg]);  // D layout (m89)
  __syncthreads();
  // kb: 16 rows x 32 cols (1 KB); vb_t: 32 d-rows x 16 s
  if (tid < 128) {
    int rowl = tid >> 3, c4 = (tid & 7) * 4;
    u16x4 v = *(const u16x4*)&O[rowl * OSTRIDE + c4];
    *(u16x4*)&kb[(size_t)(row0 + rowl) * 32 + c4] = v;
  } else if (tid < 192) {
    int t = tid - 128;
    int d = t >> 1, s8 = (t & 1) * 8;
    ushort8 v;
    #pragma unroll
    for (int j = 0; j < 8; j++) v[j] = O[(s8 + j) * OSTRIDE + 32 + d];
    int ra = row0 >> 10, sl0 = row0 & 1023;
    *(ushort8*)&vb_t[((size_t)(ra * 32) + d) * S_DIM + sl0 + s8] = v;
  }
}

// ---------- attn2: pool2 (q projection) + QK^T MFMA + softmax + PV MFMA, one block per r ----------
__global__ __launch_bounds__(256) void attn2_kernel(const unsigned short* __restrict__ kb,
                                                    const unsigned short* __restrict__ vb_t,
                                                    const float* __restrict__ psum,
                                                    const float* __restrict__ pmask,
                                                    const float* __restrict__ Wq,
                                                    const float* __restrict__ bias,
                                                    float* __restrict__ wavg) {
  int r = blockIdx.x, tid = threadIdx.x;
  int w = tid >> 6, lane = tid & 63, g = lane >> 4, lr = lane & 15;
  __shared__ float qa[256];
  __shared__ float qsp[8 * 33];      // padded q[h][k]
  __shared__ float lgp[8 * 1028];    // padded logits/P [h][s]
  __shared__ float paccL[8 * 64 * 4];
  __shared__ float denom[8];
  // ---- pool2: q_avg -> q projection (qproj kept in LDS only) ----
  float s4 = psum[(r * 4 + 0) * 256 + tid] + psum[(r * 4 + 1) * 256 + tid] +
             psum[(r * 4 + 2) * 256 + tid] + psum[(r * 4 + 3) * 256 + tid];
  float msum = pmask[r * 4] + pmask[r * 4 + 1] + pmask[r * 4 + 2] + pmask[r * 4 + 3];
  qa[tid] = s4 / (msum + EPSV);
  __syncthreads();
  float qacc = 0.f;
  #pragma unroll 8
  for (int d = 0; d < 256; d++) qacc += qa[d] * Wq[d * 256 + tid];
  qsp[(tid >> 5) * 33 + (tid & 31)] = qacc * 0.17677669529663687f;  // h=tid>>5, k=tid&31
  __syncthreads();
  // ---- QK^T via MFMA: A = K rows [s][k], B = q [k][h] ----
  ushort8 uq;
  #pragma unroll
  for (int j = 0; j < 8; j++)
    uq[j] = (lr < 8) ? f2bf(qsp[lr * 33 + g * 8 + j]) : (unsigned short)0;
  bf16x8 qf = __builtin_bit_cast(bf16x8, uq);
  for (int i = 0; i < 16; i++) {
    int rt = w * 16 + i;
    bf16x8 af = ldfrag(&kb[((size_t)r * S_DIM + rt * 16 + lr) * 32 + g * 8]);
    f32x4 d4 = {};
    d4 = __builtin_amdgcn_mfma_f32_16x16x32_bf16(af, qf, d4, 0, 0, 0);
    if (lr < 8) {
      #pragma unroll
      for (int rg = 0; rg < 4; rg++) {
        int sv = rt * 16 + g * 4 + rg;   // D: row=s=(lane>>4)*4+reg, col=h=lane&15
        lgp[lr * 1028 + sv] = d4[rg] + bias[r * S_DIM + sv];
      }
    }
  }
  __syncthreads();
  // ---- softmax per head (wave w handles h = 2w, 2w+1) ----
  for (int hh = 0; hh < 2; hh++) {
    int h = w * 2 + hh;
    float mx = -1e30f;
    #pragma unroll
    for (int i = 0; i < 16; i++) mx = fmaxf(mx, lgp[h * 1028 + lane + i * 64]);
    for (int off = 32; off; off >>= 1) mx = fmaxf(mx, __shfl_xor(mx, off));
    float sum = 0.f;
    #pragma unroll
    for (int i = 0; i < 16; i++) {
      float e = __expf(lgp[h * 1028 + lane + i * 64] - mx);
      lgp[h * 1028 + lane + i * 64] = e;
      sum += e;
    }
    for (int off = 32; off; off >>= 1) sum += __shfl_xor(sum, off);
    if (lane == 0) denom[h] = sum;
  }
  __syncthreads();
  // ---- PV via MFMA: A = P [h][s], B = V_t [s][d]; wave w does ks = 8w..8w+7 ----
  f32x4 pv[2] = {};
  for (int kk = 0; kk < 8; kk++) {
    int ks = w * 8 + kk;
    bf16x8 pa;
    if (lr < 8) {
      const float4* pp = (const float4*)&lgp[lr * 1028 + ks * 32 + g * 8];
      pa = pack8(*(const float4*)&pp[0], *(const float4*)&pp[1]);
    } else {
      pa = __builtin_bit_cast(bf16x8, (ushort8)(unsigned short)0);
    }
    #pragma unroll
    for (int ct = 0; ct < 2; ct++) {
      bf16x8 vf = ldfrag(&vb_t[((size_t)(r * 32) + ct * 16 + lr) * S_DIM + ks * 32 + g * 8]);
      pv[ct] = __builtin_amdgcn_mfma_f32_16x16x32_bf16(pa, vf, pv[ct], 0, 0, 0);
    }
  }
  *(f32x4*)&paccL[((w * 2 + 0) * 64 + lane) * 4] = pv[0];
  *(f32x4*)&paccL[((w * 2 + 1) * 64 + lane) * 4] = pv[1];
  __syncthreads();
  // ---- cross-wave reduce + divide ----
  {
    int h = tid >> 5, d = tid & 31;
    int ct = d >> 4, l2 = (h >> 2) * 16 + (d & 15), rg = h & 3;
    float sum = 0.f;
    #pragma unroll
    for (int w4 = 0; w4 < 4; w4++) sum += paccL[((w4 * 2 + ct) * 64 + l2) * 4 + rg];
    wavg[r * 256 + tid] = __fdividef(sum, denom[h]);
  }
}

// ---------- gate3: 64-row tiles, B from L2 per k-step, XCD-swizzled ----------
template <int USE_BF16>
__global__ __launch_bounds__(512, 4) void gate3_kernel(const float* __restrict__ q_data,
                                                       const unsigned short* __restrict__ qb16,
                                                       const unsigned short* __restrict__ wg,
                                                       const unsigned short* __restrict__ wo,
                                                       const float* __restrict__ bgv,
                                                       const float* __restrict__ bov,
                                                       const float* __restrict__ wavg,
                                                       float* __restrict__ outp) {
  __shared__ unsigned short AsG[64 * ASTRIDE];
  __shared__ float wavs[256];
  __shared__ float bgs[256];
  __shared__ float bos[256];
  int bid0 = blockIdx.x;
  int bid = (bid0 & 7) * 512 + (bid0 >> 3);  // XCD-bijective (nwg=4096)
  int r = bid >> 4, sc = bid & 15;
  int tid = threadIdx.x;
  int wave = tid >> 6, lane = tid & 63, g = lane >> 4, lr = lane & 15;
  int row0g = r * S_DIM + sc * 64;
  if (tid < 256) {
    wavs[tid] = wavg[r * 256 + tid];
    bgs[tid] = bgv[tid];
    bos[tid] = bov[tid];
  }
  // stage A tile (64 rows x 256 bf16): 2048 x 16B chunks
  #pragma unroll
  for (int i = 0; i < 4; i++) {
    int c = i * 512 + tid;
    int ra = c >> 5, cc = c & 31;
    ushort8 v;
    if (USE_BF16) {
      v = *(const ushort8*)&qb16[(size_t)(row0g + ra) * DMODEL + cc * 8];
    } else {
      const float4* p = (const float4*)&q_data[(size_t)(row0g + ra) * DMODEL + cc * 8];
      v = __builtin_bit_cast(ushort8, pack8(p[0], p[1]));
    }
    *(ushort8*)&AsG[ra * ASTRIDE + cc * 8] = v;
  }
  __syncthreads();
  // GEMM1: X @ Wg ; wave owns ct = 2*wave, 2*wave+1; B streamed from L2
  f32x4 acc[4][2] = {};
  for (int ks = 0; ks < 8; ks++) {
    bf16x8 b0 = ldfrag(&wg[((ks * 16 + 2 * wave) << 9) + lane * 8]);
    bf16x8 b1 = ldfrag(&wg[((ks * 16 + 2 * wave + 1) << 9) + lane * 8]);
    bf16x8 af[4];
    #pragma unroll
    for (int rt = 0; rt < 4; rt++)
      af[rt] = ldfrag(&AsG[(rt * 16 + lr) * ASTRIDE + ks * 32 + g * 8]);
    #pragma unroll
    for (int rt = 0; rt < 4; rt++) {
      acc[rt][0] = __builtin_amdgcn_mfma_f32_16x16x32_bf16(af[rt], b0, acc[rt][0], 0, 0, 0);
      acc[rt][1] = __builtin_amdgcn_mfma_f32_16x16x32_bf16(af[rt], b1, acc[rt][1], 0, 0, 0);
    }
  }
  __syncthreads();  // all GEMM1 reads of AsG done
  // gating epilogue -> G overwrites AsG
  #pragma unroll
  for (int rt = 0; rt < 4; rt++) {
    #pragma unroll
    for (int c0 = 0; c0 < 2; c0++) {
      int col = (wave * 2 + c0) * 16 + lr;
      float wv = wavs[col];
      float bgc = bgs[col];
      #pragma unroll
      for (int rg = 0; rg < 4; rg++) {
        int row = rt * 16 + g * 4 + rg;
        float x = acc[rt][c0][rg] + bgc;
        float sg = __fdividef(1.0f, 1.0f + __expf(-x));
        AsG[row * ASTRIDE + col] = f2bf(sg * wv);
      }
    }
  }
  __syncthreads();
  // GEMM2: G @ Wo
  f32x4 acc2[4][2] = {};
  for (int ks = 0; ks < 8; ks++) {
    bf16x8 b0 = ldfrag(&wo[((ks * 16 + 2 * wave) << 9) + lane * 8]);
    bf16x8 b1 = ldfrag(&wo[((ks * 16 + 2 * wave + 1) << 9) + lane * 8]);
    bf16x8 af[4];
    #pragma unroll
    for (int rt = 0; rt < 4; rt++)
      af[rt] = ldfrag(&AsG[(rt * 16 + lr) * ASTRIDE + ks * 32 + g * 8]);
    #pragma unroll
    for (int rt = 0; rt < 4; rt++) {
      acc2[rt][0] = __builtin_amdgcn_mfma_f32_16x16x32_bf16(af[rt], b0, acc2[rt][0], 0, 0, 0);
      acc2[rt][1] = __builtin_amdgcn_mfma_f32_16x16x32_bf16(af[rt], b1, acc2[rt][1], 0, 0, 0);
    }
  }
  #pragma unroll
  for (int rt = 0; rt < 4; rt++) {
    #pragma unroll
    for (int c0 = 0; c0 < 2; c0++) {
      int col = (wave * 2 + c0) * 16 + lr;
      float boc = bos[col];
      #pragma unroll
      for (int rg = 0; rg < 4; rg++) {
        int row = rt * 16 + g * 4 + rg;
        outp[(size_t)(row0g + row) * DMODEL + col] = acc2[rt][c0][rg] + boc;
      }
    }
  }
}

extern "C" void kernel_launch(void* const* d_in, const int* in_sizes, int n_in,
                              void* d_out, int out_size, void* d_ws, size_t ws_size,
                              hipStream_t stream) {
  const float* q_data = (const float*)d_in[0];
  const float* m_data = (const float*)d_in[1];
  const float* q_mask = (const float*)d_in[2];
  const float* bias   = (const float*)d_in[3];
  const float* Wq     = (const float*)d_in[4];
  const float* Wk     = (const float*)d_in[5];
  const float* Wv     = (const float*)d_in[6];
  const float* Wo     = (const float*)d_in[7];
  const float* bo     = (const float*)d_in[8];
  const float* Wg     = (const float*)d_in[9];
  const float* bg     = (const float*)d_in[10];
  float* outp = (float*)d_out;

  char* ws = (char*)d_ws;
  unsigned short* kb      = (unsigned short*)(ws + 0);          // 16 MB
  unsigned short* vb_t    = (unsigned short*)(ws + 16777216);   // 16 MB (transposed [r][d][s])
  unsigned short* wkv     = (unsigned short*)(ws + 33554432);   // 32 KB
  unsigned short* wg_pack = (unsigned short*)(ws + 33587200);   // 128 KB
  unsigned short* wo_pack = (unsigned short*)(ws + 33718272);   // 128 KB
  float* psum  = (float*)(ws + 33849344);                       // 1 MB
  float* pmask = (float*)(ws + 34897920);                       // 4 KB
  float* wavg  = (float*)(ws + 35164160);                       // 256 KB
  const size_t QB16_OFF = 35651584;
  const size_t QB16_BYTES = (size_t)R_DIM * S_DIM * DMODEL * 2; // 134 MB
  bool use_echo = ws_size >= QB16_OFF + QB16_BYTES;
  unsigned short* qb16 = use_echo ? (unsigned short*)(ws + QB16_OFF) : nullptr;

  pack_all_kernel<<<576, 256, 0, stream>>>(Wk, Wv, Wg, Wo, wkv, wg_pack, wo_pack);
  kv_kernel<<<16384, 256, 0, stream>>>(m_data, wkv, kb, vb_t);
  if (use_echo)
    pool_kernel<1><<<1024, 512, 0, stream>>>(q_data, q_mask, psum, pmask, qb16);
  else
    pool_kernel<0><<<1024, 512, 0, stream>>>(q_data, q_mask, psum, pmask, nullptr);
  attn2_kernel<<<256, 256, 0, stream>>>(kb, vb_t, psum, pmask, Wq, bias, wavg);
  if (use_echo)
    gate3_kernel<1><<<4096, 512, 0, stream>>>(q_data, qb16, wg_pack, wo_pack, bg, bo, wavg, outp);
  else
    gate3_kernel<0><<<4096, 512, 0, stream>>>(q_data, nullptr, wg_pack, wo_pack, bg, bo, wavg, outp);
}

// Round 13
// 306.167 us; speedup vs baseline: 1.0115x; 1.0115x over previous
//
#include <hip/hip_runtime.h>
#include <stdint.h>

typedef __bf16 bf16x8 __attribute__((ext_vector_type(8)));
typedef float f32x4 __attribute__((ext_vector_type(4)));
typedef unsigned short ushort8 __attribute__((ext_vector_type(8)));
typedef unsigned short u16x4 __attribute__((ext_vector_type(4)));

#define S_DIM 1024
#define R_DIM 256
#define DMODEL 256
#define EPSV 9.5367431640625e-07f
#define ASTRIDE 264  // 256 + 8 bf16 pad
#define OSTRIDE 72   // 64 + 8 pad

__device__ __forceinline__ unsigned short f2bf(float f) {
  uint32_t u = __float_as_uint(f);
  u += 0x7fffu + ((u >> 16) & 1u);
  return (unsigned short)(u >> 16);
}
__device__ __forceinline__ float bf2f(unsigned short s) {
  return __uint_as_float(((uint32_t)s) << 16);
}
__device__ __forceinline__ bf16x8 ldfrag(const unsigned short* p) {
  return __builtin_bit_cast(bf16x8, *(const ushort8*)p);
}
__device__ __forceinline__ bf16x8 pack8(float4 a, float4 b) {
  ushort8 u;
  u[0] = f2bf(a.x); u[1] = f2bf(a.y); u[2] = f2bf(a.z); u[3] = f2bf(a.w);
  u[4] = f2bf(b.x); u[5] = f2bf(b.y); u[6] = f2bf(b.z); u[7] = f2bf(b.w);
  return __builtin_bit_cast(bf16x8, u);
}

// ---------- all weight packing in one launch ----------
// B-frag layout: elem j of lane l for (kstep,ct) = W[kstep*32+(l>>4)*8+j][ct*16+(l&15)]
__global__ __launch_bounds__(256) void pack_all_kernel(const float* __restrict__ Wk,
                                                       const float* __restrict__ Wv,
                                                       const float* __restrict__ Wg,
                                                       const float* __restrict__ Wo,
                                                       unsigned short* __restrict__ wkv,
                                                       unsigned short* __restrict__ wg_p,
                                                       unsigned short* __restrict__ wo_p) {
  int bid = blockIdx.x;
  int tid = threadIdx.x;
  if (bid < 64) {
    int idx = bid * 256 + tid;
    int j = idx & 7, lane = (idx >> 3) & 63, t = idx >> 9;
    int ct = t & 3, kstep = t >> 2;
    int k = kstep * 32 + ((lane >> 4) << 3) + j;
    int col = ct * 16 + (lane & 15);
    float w = (col < 32) ? Wk[k * 32 + col] : Wv[k * 32 + (col - 32)];
    wkv[idx] = f2bf(w);
  } else {
    const float* W = (bid < 320) ? Wg : Wo;
    unsigned short* out = (bid < 320) ? wg_p : wo_p;
    int idx = ((bid < 320) ? (bid - 64) : (bid - 320)) * 256 + tid;
    int j = idx & 7, lane = (idx >> 3) & 63, t = idx >> 9;
    int ct = t & 15, kstep = t >> 4;
    int k = kstep * 32 + ((lane >> 4) << 3) + j;
    int col = ct * 16 + (lane & 15);
    out[idx] = f2bf(W[k * 256 + col]);
  }
}

// ---------- kv projection: BM=32, 16.9 KB LDS -> 8 blocks/CU (round-9 form) ----------
__global__ __launch_bounds__(256, 8) void kv_kernel(const float* __restrict__ m_data,
                                                    const unsigned short* __restrict__ wkv,
                                                    unsigned short* __restrict__ kb,
                                                    unsigned short* __restrict__ vb_t) {
  __shared__ __align__(16) unsigned short As[32 * ASTRIDE];  // reused as O [32][OSTRIDE]
  int bid = blockIdx.x;
  int tid = threadIdx.x;
  int wave = tid >> 6, lane = tid & 63;
  int g = lane >> 4, lr = lane & 15;
  int row0 = bid * 32;
  #pragma unroll
  for (int i = 0; i < 4; i++) {
    int c = i * 256 + tid;
    int ra = c >> 5, cc = c & 31;
    const float4* p = (const float4*)&m_data[(size_t)(row0 + ra) * DMODEL + cc * 8];
    *(ushort8*)&As[ra * ASTRIDE + cc * 8] = __builtin_bit_cast(ushort8, pack8(p[0], p[1]));
  }
  __syncthreads();
  int rt = wave >> 1, cp = (wave & 1) * 2;
  f32x4 acc[2] = {};
  #pragma unroll
  for (int ks = 0; ks < 8; ks++) {
    bf16x8 af = ldfrag(&As[(rt * 16 + lr) * ASTRIDE + ks * 32 + g * 8]);
    #pragma unroll
    for (int cc2 = 0; cc2 < 2; cc2++) {
      bf16x8 bf = ldfrag(&wkv[((ks * 4 + cp + cc2) << 9) + lane * 8]);
      acc[cc2] = __builtin_amdgcn_mfma_f32_16x16x32_bf16(af, bf, acc[cc2], 0, 0, 0);
    }
  }
  __syncthreads();
  unsigned short* O = As;
  #pragma unroll
  for (int cc2 = 0; cc2 < 2; cc2++) {
    #pragma unroll
    for (int rg = 0; rg < 4; rg++) {
      O[(rt * 16 + g * 4 + rg) * OSTRIDE + (cp + cc2) * 16 + lr] = f2bf(acc[cc2][rg]);  // D layout (m89)
    }
  }
  __syncthreads();
  {
    int rowl = tid >> 3, c4 = (tid & 7) * 4;
    u16x4 v = *(const u16x4*)&O[rowl * OSTRIDE + c4];
    *(u16x4*)&kb[(size_t)(row0 + rowl) * 32 + c4] = v;
  }
  if (tid < 128) {
    int d = tid >> 2, s8 = (tid & 3) * 8;
    ushort8 v;
    #pragma unroll
    for (int j = 0; j < 8; j++) v[j] = O[(s8 + j) * OSTRIDE + 32 + d];
    int ra = row0 >> 10, sl0 = row0 & 1023;
    *(ushort8*)&vb_t[((size_t)(ra * 32) + d) * S_DIM + sl0 + s8] = v;
  }
}

// ---------- poolgate: masked-pool partials + GEMM1(X@Wg) + sigmoid -> G (bf16) ----------
// grid 4096: r = bid>>4, sc = bid&15 (64 rows each); 512 thr = 8 waves
template <int WRITE_G>
__global__ __launch_bounds__(512) void poolgate_kernel(const float* __restrict__ q_data,
                                                       const float* __restrict__ q_mask,
                                                       const unsigned short* __restrict__ wg,
                                                       const float* __restrict__ bgv,
                                                       float* __restrict__ psum,
                                                       float* __restrict__ pmask,
                                                       unsigned short* __restrict__ Gout) {
  __shared__ unsigned short AsG[64 * ASTRIDE];
  __shared__ float mlds[64];
  __shared__ f32x4 red[8 * 64];
  __shared__ float bgs[256];
  int bid = blockIdx.x;
  int r = bid >> 4, sc = bid & 15;
  int tid = threadIdx.x;
  int wave = tid >> 6, lane = tid & 63, g = lane >> 4, lr = lane & 15;
  int row0g = r * S_DIM + sc * 64;
  if (tid < 64) mlds[tid] = q_mask[row0g + tid];
  if (tid >= 256) bgs[tid - 256] = bgv[tid - 256];
  __syncthreads();
  if (tid < 64) {
    float ms = mlds[tid];
    for (int off = 32; off; off >>= 1) ms += __shfl_down(ms, off);
    if (tid == 0) pmask[r * 16 + sc] = ms;
  }
  // stage A (64x256 fp32 -> bf16 LDS) + masked column partial sums
  f32x4 acc4 = {};
  int cc = tid & 63;  // 4-float column chunk; wave reads one full row per iter (coalesced 1KB)
  #pragma unroll
  for (int i = 0; i < 8; i++) {
    int ra = i * 8 + wave;
    float4 v = *(const float4*)&q_data[(size_t)(row0g + ra) * DMODEL + cc * 4];
    float mm = mlds[ra];
    acc4[0] += v.x * mm; acc4[1] += v.y * mm;
    acc4[2] += v.z * mm; acc4[3] += v.w * mm;
    u16x4 e;
    e[0] = f2bf(v.x); e[1] = f2bf(v.y); e[2] = f2bf(v.z); e[3] = f2bf(v.w);
    *(u16x4*)&AsG[ra * ASTRIDE + cc * 4] = e;
  }
  red[wave * 64 + cc] = acc4;
  __syncthreads();
  if (tid < 256) {
    float sum = 0.f;
    #pragma unroll
    for (int k = 0; k < 8; k++) sum += red[k * 64 + (tid >> 2)][tid & 3];
    psum[((size_t)(r * 16 + sc)) * 256 + tid] = sum;
  }
  if (WRITE_G) {
    // GEMM1: X @ Wg; wave owns ct = 2*wave, 2*wave+1
    f32x4 acc[4][2] = {};
    for (int ks = 0; ks < 8; ks++) {
      bf16x8 b0 = ldfrag(&wg[((ks * 16 + 2 * wave) << 9) + lane * 8]);
      bf16x8 b1 = ldfrag(&wg[((ks * 16 + 2 * wave + 1) << 9) + lane * 8]);
      bf16x8 af[4];
      #pragma unroll
      for (int rt = 0; rt < 4; rt++)
        af[rt] = ldfrag(&AsG[(rt * 16 + lr) * ASTRIDE + ks * 32 + g * 8]);
      #pragma unroll
      for (int rt = 0; rt < 4; rt++) {
        acc[rt][0] = __builtin_amdgcn_mfma_f32_16x16x32_bf16(af[rt], b0, acc[rt][0], 0, 0, 0);
        acc[rt][1] = __builtin_amdgcn_mfma_f32_16x16x32_bf16(af[rt], b1, acc[rt][1], 0, 0, 0);
      }
    }
    __syncthreads();  // all GEMM1 reads of AsG done
    #pragma unroll
    for (int rt = 0; rt < 4; rt++) {
      #pragma unroll
      for (int c0 = 0; c0 < 2; c0++) {
        int col = (wave * 2 + c0) * 16 + lr;
        float bgc = bgs[col];
        #pragma unroll
        for (int rg = 0; rg < 4; rg++) {
          int row = rt * 16 + g * 4 + rg;  // D layout (m89)
          float x = acc[rt][c0][rg] + bgc;
          AsG[row * ASTRIDE + col] = f2bf(__fdividef(1.0f, 1.0f + __expf(-x)));
        }
      }
    }
    __syncthreads();
    // coalesced G write-out (replaces the old qb16 echo byte-for-byte)
    #pragma unroll
    for (int i = 0; i < 4; i++) {
      int c = i * 512 + tid;
      int ra = c >> 5, c8 = (c & 31) * 8;
      *(ushort8*)&Gout[(size_t)(row0g + ra) * DMODEL + c8] = *(const ushort8*)&AsG[ra * ASTRIDE + c8];
    }
  }
}

// ---------- attn2: pool2 (q projection) + QK^T MFMA + softmax + PV MFMA, one block per r ----------
__global__ __launch_bounds__(256) void attn2_kernel(const unsigned short* __restrict__ kb,
                                                    const unsigned short* __restrict__ vb_t,
                                                    const float* __restrict__ psum,
                                                    const float* __restrict__ pmask,
                                                    const float* __restrict__ Wq,
                                                    const float* __restrict__ bias,
                                                    float* __restrict__ wavg) {
  int r = blockIdx.x, tid = threadIdx.x;
  int w = tid >> 6, lane = tid & 63, g = lane >> 4, lr = lane & 15;
  __shared__ float qa[256];
  __shared__ float qsp[8 * 33];
  __shared__ float lgp[8 * 1028];
  __shared__ float paccL[8 * 64 * 4];
  __shared__ float denom[8];
  float s4 = 0.f;
  #pragma unroll
  for (int p = 0; p < 16; p++) s4 += psum[((size_t)(r * 16 + p)) * 256 + tid];
  float msum = 0.f;
  #pragma unroll
  for (int p = 0; p < 16; p++) msum += pmask[r * 16 + p];
  qa[tid] = s4 / (msum + EPSV);
  __syncthreads();
  float qacc = 0.f;
  #pragma unroll 8
  for (int d = 0; d < 256; d++) qacc += qa[d] * Wq[d * 256 + tid];
  qsp[(tid >> 5) * 33 + (tid & 31)] = qacc * 0.17677669529663687f;
  __syncthreads();
  ushort8 uq;
  #pragma unroll
  for (int j = 0; j < 8; j++)
    uq[j] = (lr < 8) ? f2bf(qsp[lr * 33 + g * 8 + j]) : (unsigned short)0;
  bf16x8 qf = __builtin_bit_cast(bf16x8, uq);
  for (int i = 0; i < 16; i++) {
    int rt = w * 16 + i;
    bf16x8 af = ldfrag(&kb[((size_t)r * S_DIM + rt * 16 + lr) * 32 + g * 8]);
    f32x4 d4 = {};
    d4 = __builtin_amdgcn_mfma_f32_16x16x32_bf16(af, qf, d4, 0, 0, 0);
    if (lr < 8) {
      #pragma unroll
      for (int rg = 0; rg < 4; rg++) {
        int sv = rt * 16 + g * 4 + rg;
        lgp[lr * 1028 + sv] = d4[rg] + bias[r * S_DIM + sv];
      }
    }
  }
  __syncthreads();
  for (int hh = 0; hh < 2; hh++) {
    int h = w * 2 + hh;
    float mx = -1e30f;
    #pragma unroll
    for (int i = 0; i < 16; i++) mx = fmaxf(mx, lgp[h * 1028 + lane + i * 64]);
    for (int off = 32; off; off >>= 1) mx = fmaxf(mx, __shfl_xor(mx, off));
    float sum = 0.f;
    #pragma unroll
    for (int i = 0; i < 16; i++) {
      float e = __expf(lgp[h * 1028 + lane + i * 64] - mx);
      lgp[h * 1028 + lane + i * 64] = e;
      sum += e;
    }
    for (int off = 32; off; off >>= 1) sum += __shfl_xor(sum, off);
    if (lane == 0) denom[h] = sum;
  }
  __syncthreads();
  f32x4 pv[2] = {};
  for (int kk = 0; kk < 8; kk++) {
    int ks = w * 8 + kk;
    bf16x8 pa;
    if (lr < 8) {
      const float4* pp = (const float4*)&lgp[lr * 1028 + ks * 32 + g * 8];
      pa = pack8(*(const float4*)&pp[0], *(const float4*)&pp[1]);
    } else {
      pa = __builtin_bit_cast(bf16x8, (ushort8)(unsigned short)0);
    }
    #pragma unroll
    for (int ct = 0; ct < 2; ct++) {
      bf16x8 vf = ldfrag(&vb_t[((size_t)(r * 32) + ct * 16 + lr) * S_DIM + ks * 32 + g * 8]);
      pv[ct] = __builtin_amdgcn_mfma_f32_16x16x32_bf16(pa, vf, pv[ct], 0, 0, 0);
    }
  }
  *(f32x4*)&paccL[((w * 2 + 0) * 64 + lane) * 4] = pv[0];
  *(f32x4*)&paccL[((w * 2 + 1) * 64 + lane) * 4] = pv[1];
  __syncthreads();
  {
    int h = tid >> 5, d = tid & 31;
    int ct = d >> 4, l2 = (h >> 2) * 16 + (d & 15), rg = h & 3;
    float sum = 0.f;
    #pragma unroll
    for (int w4 = 0; w4 < 4; w4++) sum += paccL[((w4 * 2 + ct) * 64 + l2) * 4 + rg];
    wavg[r * 256 + tid] = __fdividef(sum, denom[h]);
  }
}

// ---------- gate4: read G (L3-hot), ⊙ wavg, GEMM2 @ Wo, + bo, write out ----------
__global__ __launch_bounds__(512) void gate4_kernel(const unsigned short* __restrict__ G,
                                                    const unsigned short* __restrict__ wo,
                                                    const float* __restrict__ bov,
                                                    const float* __restrict__ wavg,
                                                    float* __restrict__ outp) {
  __shared__ unsigned short AsG[64 * ASTRIDE];
  __shared__ float wavs[256];
  __shared__ float bos[256];
  int bid = blockIdx.x;
  int r = bid >> 4, sc = bid & 15;
  int tid = threadIdx.x;
  int wave = tid >> 6, lane = tid & 63, g = lane >> 4, lr = lane & 15;
  int row0g = r * S_DIM + sc * 64;
  if (tid < 256) wavs[tid] = wavg[r * 256 + tid];
  else           bos[tid - 256] = bov[tid - 256];
  __syncthreads();
  // stage gated A: AsG[row][col] = G[row][col] * wavs[col]
  #pragma unroll
  for (int i = 0; i < 4; i++) {
    int c = i * 512 + tid;
    int ra = c >> 5, c8 = (c & 31) * 8;
    ushort8 gv = *(const ushort8*)&G[(size_t)(row0g + ra) * DMODEL + c8];
    ushort8 o;
    #pragma unroll
    for (int j = 0; j < 8; j++) o[j] = f2bf(bf2f(gv[j]) * wavs[c8 + j]);
    *(ushort8*)&AsG[ra * ASTRIDE + c8] = o;
  }
  __syncthreads();
  // GEMM2: (G ⊙ wavg) @ Wo
  f32x4 acc2[4][2] = {};
  for (int ks = 0; ks < 8; ks++) {
    bf16x8 b0 = ldfrag(&wo[((ks * 16 + 2 * wave) << 9) + lane * 8]);
    bf16x8 b1 = ldfrag(&wo[((ks * 16 + 2 * wave + 1) << 9) + lane * 8]);
    bf16x8 af[4];
    #pragma unroll
    for (int rt = 0; rt < 4; rt++)
      af[rt] = ldfrag(&AsG[(rt * 16 + lr) * ASTRIDE + ks * 32 + g * 8]);
    #pragma unroll
    for (int rt = 0; rt < 4; rt++) {
      acc2[rt][0] = __builtin_amdgcn_mfma_f32_16x16x32_bf16(af[rt], b0, acc2[rt][0], 0, 0, 0);
      acc2[rt][1] = __builtin_amdgcn_mfma_f32_16x16x32_bf16(af[rt], b1, acc2[rt][1], 0, 0, 0);
    }
  }
  #pragma unroll
  for (int rt = 0; rt < 4; rt++) {
    #pragma unroll
    for (int c0 = 0; c0 < 2; c0++) {
      int col = (wave * 2 + c0) * 16 + lr;
      float boc = bos[col];
      #pragma unroll
      for (int rg = 0; rg < 4; rg++) {
        int row = rt * 16 + g * 4 + rg;  // D layout (m89)
        outp[(size_t)(row0g + row) * DMODEL + col] = acc2[rt][c0][rg] + boc;
      }
    }
  }
}

// ---------- gate3 fallback (fp32 q_data path; used only if ws lacks room for G) ----------
__global__ __launch_bounds__(512, 4) void gate3_kernel(const float* __restrict__ q_data,
                                                       const unsigned short* __restrict__ wg,
                                                       const unsigned short* __restrict__ wo,
                                                       const float* __restrict__ bgv,
                                                       const float* __restrict__ bov,
                                                       const float* __restrict__ wavg,
                                                       float* __restrict__ outp) {
  __shared__ unsigned short AsG[64 * ASTRIDE];
  __shared__ float wavs[256];
  __shared__ float bgs[256];
  __shared__ float bos[256];
  int bid = blockIdx.x;
  int r = bid >> 4, sc = bid & 15;
  int tid = threadIdx.x;
  int wave = tid >> 6, lane = tid & 63, g = lane >> 4, lr = lane & 15;
  int row0g = r * S_DIM + sc * 64;
  if (tid < 256) {
    wavs[tid] = wavg[r * 256 + tid];
    bgs[tid] = bgv[tid];
    bos[tid] = bov[tid];
  }
  #pragma unroll
  for (int i = 0; i < 4; i++) {
    int c = i * 512 + tid;
    int ra = c >> 5, cc = c & 31;
    const float4* p = (const float4*)&q_data[(size_t)(row0g + ra) * DMODEL + cc * 8];
    *(ushort8*)&AsG[ra * ASTRIDE + cc * 8] = __builtin_bit_cast(ushort8, pack8(p[0], p[1]));
  }
  __syncthreads();
  f32x4 acc[4][2] = {};
  for (int ks = 0; ks < 8; ks++) {
    bf16x8 b0 = ldfrag(&wg[((ks * 16 + 2 * wave) << 9) + lane * 8]);
    bf16x8 b1 = ldfrag(&wg[((ks * 16 + 2 * wave + 1) << 9) + lane * 8]);
    bf16x8 af[4];
    #pragma unroll
    for (int rt = 0; rt < 4; rt++)
      af[rt] = ldfrag(&AsG[(rt * 16 + lr) * ASTRIDE + ks * 32 + g * 8]);
    #pragma unroll
    for (int rt = 0; rt < 4; rt++) {
      acc[rt][0] = __builtin_amdgcn_mfma_f32_16x16x32_bf16(af[rt], b0, acc[rt][0], 0, 0, 0);
      acc[rt][1] = __builtin_amdgcn_mfma_f32_16x16x32_bf16(af[rt], b1, acc[rt][1], 0, 0, 0);
    }
  }
  __syncthreads();
  #pragma unroll
  for (int rt = 0; rt < 4; rt++) {
    #pragma unroll
    for (int c0 = 0; c0 < 2; c0++) {
      int col = (wave * 2 + c0) * 16 + lr;
      float wv = wavs[col];
      float bgc = bgs[col];
      #pragma unroll
      for (int rg = 0; rg < 4; rg++) {
        int row = rt * 16 + g * 4 + rg;
        float x = acc[rt][c0][rg] + bgc;
        float sg = __fdividef(1.0f, 1.0f + __expf(-x));
        AsG[row * ASTRIDE + col] = f2bf(sg * wv);
      }
    }
  }
  __syncthreads();
  f32x4 acc2[4][2] = {};
  for (int ks = 0; ks < 8; ks++) {
    bf16x8 b0 = ldfrag(&wo[((ks * 16 + 2 * wave) << 9) + lane * 8]);
    bf16x8 b1 = ldfrag(&wo[((ks * 16 + 2 * wave + 1) << 9) + lane * 8]);
    bf16x8 af[4];
    #pragma unroll
    for (int rt = 0; rt < 4; rt++)
      af[rt] = ldfrag(&AsG[(rt * 16 + lr) * ASTRIDE + ks * 32 + g * 8]);
    #pragma unroll
    for (int rt = 0; rt < 4; rt++) {
      acc2[rt][0] = __builtin_amdgcn_mfma_f32_16x16x32_bf16(af[rt], b0, acc2[rt][0], 0, 0, 0);
      acc2[rt][1] = __builtin_amdgcn_mfma_f32_16x16x32_bf16(af[rt], b1, acc2[rt][1], 0, 0, 0);
    }
  }
  #pragma unroll
  for (int rt = 0; rt < 4; rt++) {
    #pragma unroll
    for (int c0 = 0; c0 < 2; c0++) {
      int col = (wave * 2 + c0) * 16 + lr;
      float boc = bos[col];
      #pragma unroll
      for (int rg = 0; rg < 4; rg++) {
        int row = rt * 16 + g * 4 + rg;
        outp[(size_t)(row0g + row) * DMODEL + col] = acc2[rt][c0][rg] + boc;
      }
    }
  }
}

extern "C" void kernel_launch(void* const* d_in, const int* in_sizes, int n_in,
                              void* d_out, int out_size, void* d_ws, size_t ws_size,
                              hipStream_t stream) {
  const float* q_data = (const float*)d_in[0];
  const float* m_data = (const float*)d_in[1];
  const float* q_mask = (const float*)d_in[2];
  const float* bias   = (const float*)d_in[3];
  const float* Wq     = (const float*)d_in[4];
  const float* Wk     = (const float*)d_in[5];
  const float* Wv     = (const float*)d_in[6];
  const float* Wo     = (const float*)d_in[7];
  const float* bo     = (const float*)d_in[8];
  const float* Wg     = (const float*)d_in[9];
  const float* bg     = (const float*)d_in[10];
  float* outp = (float*)d_out;

  char* ws = (char*)d_ws;
  unsigned short* kb      = (unsigned short*)(ws + 0);          // 16 MB
  unsigned short* vb_t    = (unsigned short*)(ws + 16777216);   // 16 MB
  unsigned short* wkv     = (unsigned short*)(ws + 33554432);   // 32 KB
  unsigned short* wg_pack = (unsigned short*)(ws + 33587200);   // 128 KB
  unsigned short* wo_pack = (unsigned short*)(ws + 33718272);   // 128 KB
  float* psum  = (float*)(ws + 33849344);                       // 4 MB ([r][16][256])
  float* pmask = (float*)(ws + 38043648);                       // 16 KB ([r][16])
  float* wavg  = (float*)(ws + 38060032);                       // 256 KB
  const size_t G_OFF = 38322176;
  const size_t G_BYTES = (size_t)R_DIM * S_DIM * DMODEL * 2;    // 134 MB
  bool use_g = ws_size >= G_OFF + G_BYTES;
  unsigned short* Gbuf = use_g ? (unsigned short*)(ws + G_OFF) : nullptr;

  pack_all_kernel<<<576, 256, 0, stream>>>(Wk, Wv, Wg, Wo, wkv, wg_pack, wo_pack);
  kv_kernel<<<8192, 256, 0, stream>>>(m_data, wkv, kb, vb_t);
  if (use_g)
    poolgate_kernel<1><<<4096, 512, 0, stream>>>(q_data, q_mask, wg_pack, bg, psum, pmask, Gbuf);
  else
    poolgate_kernel<0><<<4096, 512, 0, stream>>>(q_data, q_mask, wg_pack, bg, psum, pmask, nullptr);
  attn2_kernel<<<256, 256, 0, stream>>>(kb, vb_t, psum, pmask, Wq, bias, wavg);
  if (use_g)
    gate4_kernel<<<4096, 512, 0, stream>>>(Gbuf, wo_pack, bo, wavg, outp);
  else
    gate3_kernel<<<4096, 512, 0, stream>>>(q_data, wg_pack, wo_pack, bg, bo, wavg, outp);
}